// Round 4
// baseline (686.339 us; speedup 1.0000x reference)
//
#include <hip/hip_runtime.h>
#include <hip/hip_bf16.h>
#include <math.h>

typedef __attribute__((ext_vector_type(8))) short short8;
typedef __attribute__((ext_vector_type(4))) float f32x4;

#define BATCH 16
#define IC 512
#define OC 512
#define HW 64
#define SD 512

#define LIN_SCALE 0.04419417382415922f   // 1/sqrt(512)
#define CONV_SCALE 0.014731391274719742f // 1/sqrt(4608)
#define CS2 (1.0f / 4608.0f)

// ---------------- stage 1: s[b][c] ----------------
__global__ void k_style(const float* __restrict__ style, const float* __restrict__ mod_w,
                        const float* __restrict__ mod_b, float* __restrict__ s) {
    int idx = blockIdx.x * blockDim.x + threadIdx.x;
    if (idx >= BATCH * IC) return;
    int b = idx / IC, c = idx % IC;
    const float4* st = (const float4*)(style + (size_t)b * SD);
    const float4* mw = (const float4*)(mod_w + (size_t)c * SD);
    float acc = 0.f;
#pragma unroll 4
    for (int k = 0; k < SD / 4; ++k) {
        float4 a = st[k], w = mw[k];
        acc += a.x * w.x + a.y * w.y + a.z * w.z + a.w * w.w;
    }
    s[idx] = acc * LIN_SCALE + mod_b[c];
}

// ---------------- stage 2: wsq[o][c] = sum_kk w^2 ----------------
__global__ void k_wsq(const float* __restrict__ weight, float* __restrict__ wsq) {
    int idx = blockIdx.x * blockDim.x + threadIdx.x;
    if (idx >= OC * IC) return;
    const float* w = weight + (size_t)idx * 9;
    float acc = 0.f;
#pragma unroll
    for (int k = 0; k < 9; ++k) { float v = w[k]; acc += v * v; }
    wsq[idx] = acc;
}

// ---------------- stage 3: d[b][o] ----------------
__global__ void k_demod(const float* __restrict__ s, const float* __restrict__ wsq,
                        float* __restrict__ dmod) {
    int idx = blockIdx.x * blockDim.x + threadIdx.x;
    if (idx >= BATCH * OC) return;
    int b = idx / OC, o = idx % OC;
    const float* sb = s + (size_t)b * IC;
    const float* wo = wsq + (size_t)o * IC;
    float acc = 0.f;
#pragma unroll 4
    for (int c = 0; c < IC; ++c) { float sv = sb[c]; acc = fmaf(sv * sv, wo[c], acc); }
    dmod[idx] = rsqrtf(acc * CS2 + 1e-8f);
}

// ---------------- stage 4a: wmod[b][tap][oc][ic] bf16 ----------------
// grid (OC, BATCH), 256 threads
__global__ __launch_bounds__(256) void k_wmod(
    const float* __restrict__ weight, const float* __restrict__ s,
    const float* __restrict__ dmod, __hip_bfloat16* __restrict__ wmod) {
    __shared__ float wrow[IC * 9]; // 18KB
    int oc = blockIdx.x, b = blockIdx.y;
    const float* wp = weight + (size_t)oc * IC * 9;
    for (int i = threadIdx.x; i < IC * 9; i += 256) wrow[i] = wp[i];
    __syncthreads();
    float dd = CONV_SCALE * dmod[b * OC + oc];
    const float* sb = s + (size_t)b * IC;
#pragma unroll
    for (int tap = 0; tap < 9; ++tap) {
        int icp = threadIdx.x;                 // IC/2 == 256 pairs
        int ic0 = icp * 2;
        float v0 = wrow[ic0 * 9 + tap] * (sb[ic0] * dd);
        float v1 = wrow[(ic0 + 1) * 9 + tap] * (sb[ic0 + 1] * dd);
        __hip_bfloat162 p;
        p.x = __float2bfloat16(v0);
        p.y = __float2bfloat16(v1);
        *(__hip_bfloat162*)(wmod + ((((size_t)b * 9 + tap) * OC + oc) * IC + ic0)) = p;
    }
}

// ---------------- stage 4b: MFMA implicit-GEMM grouped conv ----------------
// 512 blocks = (b:16 x ocg:4) x sp:8. block = 512 threads (8 waves).
// tile: 128 oc x (8 rows x 64 cols). waves: og=wid>>2 (64 oc each), rg=wid&3 (2 rows).
// K-loop: 16 chunks of 32 ic. x tile in LDS [ichi4][row10][col66][iclo8] bf16.
// A-frags (weights) straight from global (L2; 8 sp-blocks of one (b,ocg) share XCD).
__global__ __launch_bounds__(512, 2) void k_conv_mfma(
    const float* __restrict__ x, const __hip_bfloat16* __restrict__ wmod,
    float* __restrict__ out) {
    __shared__ short xs[4 * 10 * 66 * 8]; // 42.24 KB

    const int bid = blockIdx.x;
    const int g = bid & 63, sp = bid >> 6;   // bid%8 == g%8 for all sp -> same XCD per (b,ocg)
    const int b = g >> 2, ocg = g & 3;
    const int ocb = ocg * 128, y0 = sp * 8;

    const int t = threadIdx.x;
    const int lane = t & 63, wid = t >> 6;
    const int og = wid >> 2, rg = wid & 3;
    const int l15 = lane & 15, l4 = lane >> 4;

    f32x4 acc[4][8]; // [mtile][r*4+cg]
#pragma unroll
    for (int m = 0; m < 4; ++m)
#pragma unroll
        for (int n = 0; n < 8; ++n) acc[m][n] = (f32x4){0.f, 0.f, 0.f, 0.f};

    const float* xb = x + (size_t)b * IC * HW * HW;
    const __hip_bfloat16* wb = wmod + (size_t)b * 9 * OC * IC;

    for (int icb = 0; icb < IC; icb += 32) {
        __syncthreads();
        // ---- stage x chunk: 2640 granules of 8 ic (bf16x8, 16B) ----
        for (int i = t; i < 2640; i += 512) {
            int ichi = i / 660;
            int rem = i - ichi * 660;
            int row = rem / 66;
            int col = rem - row * 66;
            int gy = y0 + row - 1, gx = col - 1;
            float v[8];
            if ((unsigned)gy < 64u && (unsigned)gx < 64u) {
                const float* xp = xb + ((size_t)(icb + ichi * 8) * 64 + gy) * 64 + gx;
#pragma unroll
                for (int j = 0; j < 8; ++j) v[j] = xp[(size_t)j * 4096];
            } else {
#pragma unroll
                for (int j = 0; j < 8; ++j) v[j] = 0.f;
            }
            short8 pk;
#pragma unroll
            for (int j = 0; j < 8; ++j) {
                __hip_bfloat16 bh = __float2bfloat16(v[j]);
                pk[j] = *reinterpret_cast<short*>(&bh);
            }
            *(short8*)&xs[i * 8] = pk;
        }
        __syncthreads();

#pragma unroll
        for (int kw = 0; kw < 3; ++kw) {
            short8 A[3][4];
#pragma unroll
            for (int kh = 0; kh < 3; ++kh)
#pragma unroll
                for (int mt = 0; mt < 4; ++mt) {
                    int oc = ocb + og * 64 + mt * 16 + l15;
                    int tap = kh * 3 + kw;
                    A[kh][mt] = *(const short8*)(wb + (((size_t)tap * OC + oc) * IC + icb + l4 * 8));
                }
#pragma unroll
            for (int cg = 0; cg < 4; ++cg) {
                short8 Bf[4];
#pragma unroll
                for (int ir = 0; ir < 4; ++ir) {
                    int row = rg * 2 + ir;          // covers out rows rg*2+{0,1}, kh-1..+1
                    int col = cg * 16 + l15 + kw;   // lds col = gx+1
                    Bf[ir] = *(const short8*)&xs[(((l4 * 10 + row) * 66 + col)) * 8];
                }
#pragma unroll
                for (int kh = 0; kh < 3; ++kh)
#pragma unroll
                    for (int mt = 0; mt < 4; ++mt)
#pragma unroll
                        for (int r = 0; r < 2; ++r)
                            acc[mt][r * 4 + cg] = __builtin_amdgcn_mfma_f32_16x16x32_bf16(
                                A[kh][mt], Bf[r + kh], acc[mt][r * 4 + cg], 0, 0, 0);
            }
        }
    }

    // ---- epilogue: C/D layout col=lane&15 (px), row=(lane>>4)*4+q (oc) ----
#pragma unroll
    for (int mt = 0; mt < 4; ++mt)
#pragma unroll
        for (int r = 0; r < 2; ++r)
#pragma unroll
            for (int cg = 0; cg < 4; ++cg) {
                f32x4 v = acc[mt][r * 4 + cg];
                int y = y0 + rg * 2 + r;
                int xcol = cg * 16 + l15;
#pragma unroll
                for (int q = 0; q < 4; ++q) {
                    int oc = ocb + og * 64 + mt * 16 + l4 * 4 + q;
                    out[(((size_t)b * OC + oc) * HW + y) * HW + xcol] = v[q];
                }
            }
}

// ---------------- fp32 fallback conv (round-0, correct) ----------------
#define OC_TILE 16
#define ROWS 4
#define ICCH 8
#define XW 67

__global__ __launch_bounds__(256) void k_conv_f32(
    const float* __restrict__ x, const float* __restrict__ weight,
    const float* __restrict__ s, const float* __restrict__ dmod,
    float* __restrict__ out) {
    __shared__ float x_lds[ICCH][ROWS + 2][XW];
    __shared__ float w_lds[OC_TILE][ICCH][9];

    const int b = blockIdx.z;
    const int ocb = blockIdx.y * OC_TILE;
    const int y0 = blockIdx.x * ROWS;

    const int t = threadIdx.x;
    const int gg = t & 63;
    const int ocg = t >> 6;
    const int row = gg >> 4;
    const int col = (gg & 15) * 4;

    float acc[4][4];
#pragma unroll
    for (int j = 0; j < 4; ++j)
#pragma unroll
        for (int i = 0; i < 4; ++i) acc[j][i] = 0.f;

    const float* xb = x + (size_t)b * IC * HW * HW;
    const float* sb = s + (size_t)b * IC;
    const float* db = dmod + (size_t)b * OC;

    for (int icb = 0; icb < IC; icb += ICCH) {
        for (int i = t; i < ICCH * 6 * 66; i += 256) {
            int ic = i / (6 * 66);
            int rem = i - ic * (6 * 66);
            int r = rem / 66;
            int cx = rem - r * 66;
            int gy = y0 + r - 1;
            int gx = cx - 1;
            float v = 0.f;
            if ((unsigned)gy < 64u && (unsigned)gx < 64u)
                v = xb[((size_t)(icb + ic) * 64 + gy) * 64 + gx];
            x_lds[ic][r][cx] = v;
        }
        for (int i = t; i < OC_TILE * ICCH * 9; i += 256) {
            int oc = i / (ICCH * 9);
            int rem = i - oc * (ICCH * 9);
            int ic = rem / 9;
            int kk = rem - ic * 9;
            float sc = CONV_SCALE * sb[icb + ic] * db[ocb + oc];
            w_lds[oc][ic][kk] = weight[((size_t)(ocb + oc) * IC + (icb + ic)) * 9 + kk] * sc;
        }
        __syncthreads();
#pragma unroll
        for (int ic = 0; ic < ICCH; ++ic)
#pragma unroll
            for (int kh = 0; kh < 3; ++kh) {
                float xv[6];
#pragma unroll
                for (int u = 0; u < 6; ++u) xv[u] = x_lds[ic][row + kh][col + u];
#pragma unroll
                for (int kw = 0; kw < 3; ++kw)
#pragma unroll
                    for (int j = 0; j < 4; ++j) {
                        float wv = w_lds[ocg * 4 + j][ic][kh * 3 + kw];
#pragma unroll
                        for (int i2 = 0; i2 < 4; ++i2)
                            acc[j][i2] = fmaf(wv, xv[i2 + kw], acc[j][i2]);
                    }
            }
        __syncthreads();
    }
#pragma unroll
    for (int j = 0; j < 4; ++j) {
        int oc = ocb + ocg * 4 + j;
        float4 v = make_float4(acc[j][0], acc[j][1], acc[j][2], acc[j][3]);
        *(float4*)(out + (((size_t)b * OC + oc) * HW + (y0 + row)) * HW + col) = v;
    }
}

extern "C" void kernel_launch(void* const* d_in, const int* in_sizes, int n_in,
                              void* d_out, int out_size, void* d_ws, size_t ws_size,
                              hipStream_t stream) {
    const float* x      = (const float*)d_in[0];
    const float* style  = (const float*)d_in[1];
    const float* weight = (const float*)d_in[2];
    const float* mod_w  = (const float*)d_in[3];
    const float* mod_b  = (const float*)d_in[4];
    float* out = (float*)d_out;

    // ws layout (floats): s[8192] | wsq[262144] | dmod[8192] | wmod bf16 (75.5MB)
    float* s    = (float*)d_ws;
    float* wsq  = s + BATCH * IC;
    float* dmod = wsq + (size_t)OC * IC;
    __hip_bfloat16* wmod = (__hip_bfloat16*)(dmod + BATCH * OC);

    const size_t need = (size_t)(BATCH * IC + OC * IC + BATCH * OC) * 4 +
                        (size_t)BATCH * 9 * OC * IC * 2;

    k_style<<<(BATCH * IC + 255) / 256, 256, 0, stream>>>(style, mod_w, mod_b, s);
    k_wsq<<<(OC * IC + 255) / 256, 256, 0, stream>>>(weight, wsq);
    k_demod<<<(BATCH * OC + 255) / 256, 256, 0, stream>>>(s, wsq, dmod);

    if (ws_size >= need) {
        dim3 wg(OC, BATCH);
        k_wmod<<<wg, 256, 0, stream>>>(weight, s, dmod, wmod);
        k_conv_mfma<<<512, 512, 0, stream>>>(x, wmod, out);
    } else {
        dim3 grid(HW / ROWS, OC / OC_TILE, BATCH);
        k_conv_f32<<<grid, 256, 0, stream>>>(x, weight, s, dmod, out);
    }
}

// Round 5
// 599.305 us; speedup vs baseline: 1.1452x; 1.1452x over previous
//
#include <hip/hip_runtime.h>
#include <hip/hip_bf16.h>
#include <math.h>

typedef __attribute__((ext_vector_type(8))) short short8;
typedef __attribute__((ext_vector_type(4))) short short4v;
typedef __attribute__((ext_vector_type(4))) float f32x4;

#define BATCH 16
#define IC 512
#define OC 512
#define HW 64
#define SD 512

#define LIN_SCALE 0.04419417382415922f   // 1/sqrt(512)
#define CONV_SCALE 0.014731391274719742f // 1/sqrt(4608)
#define CS2 (1.0f / 4608.0f)

// ---------------- stage 1: s[b][c] ----------------
__global__ void k_style(const float* __restrict__ style, const float* __restrict__ mod_w,
                        const float* __restrict__ mod_b, float* __restrict__ s) {
    int idx = blockIdx.x * blockDim.x + threadIdx.x;
    if (idx >= BATCH * IC) return;
    int b = idx / IC, c = idx % IC;
    const float4* st = (const float4*)(style + (size_t)b * SD);
    const float4* mw = (const float4*)(mod_w + (size_t)c * SD);
    float acc = 0.f;
#pragma unroll 4
    for (int k = 0; k < SD / 4; ++k) {
        float4 a = st[k], w = mw[k];
        acc += a.x * w.x + a.y * w.y + a.z * w.z + a.w * w.w;
    }
    s[idx] = acc * LIN_SCALE + mod_b[c];
}

// ---------------- stage 2: wsq[o][c] = sum_kk w^2 ----------------
__global__ void k_wsq(const float* __restrict__ weight, float* __restrict__ wsq) {
    int idx = blockIdx.x * blockDim.x + threadIdx.x;
    if (idx >= OC * IC) return;
    const float* w = weight + (size_t)idx * 9;
    float acc = 0.f;
#pragma unroll
    for (int k = 0; k < 9; ++k) { float v = w[k]; acc += v * v; }
    wsq[idx] = acc;
}

// ---------------- stage 3: d[b][o] ----------------
__global__ void k_demod(const float* __restrict__ s, const float* __restrict__ wsq,
                        float* __restrict__ dmod) {
    int idx = blockIdx.x * blockDim.x + threadIdx.x;
    if (idx >= BATCH * OC) return;
    int b = idx / OC, o = idx % OC;
    const float* sb = s + (size_t)b * IC;
    const float* wo = wsq + (size_t)o * IC;
    float acc = 0.f;
#pragma unroll 4
    for (int c = 0; c < IC; ++c) { float sv = sb[c]; acc = fmaf(sv * sv, wo[c], acc); }
    dmod[idx] = rsqrtf(acc * CS2 + 1e-8f);
}

// ---------------- x transpose prepass: xt[b][66][66][512] bf16, zero halo ----------------
// grid (66, 16), 256 threads. Interior row r: transpose x[b][:, r-1, :] (512 ic x 64 px).
__global__ __launch_bounds__(256) void k_xt(const float* __restrict__ x,
                                            __hip_bfloat16* __restrict__ xt) {
    const int r = blockIdx.x, b = blockIdx.y;
    __hip_bfloat16* dst = xt + ((size_t)b * 66 + r) * 66 * 512;
    const int t = threadIdx.x;

    if (r == 0 || r == 65) {
        short4v z = {0, 0, 0, 0};
        for (int i = t; i < 66 * 512 / 4; i += 256) ((short4v*)dst)[i] = z;
        return;
    }
    __shared__ __hip_bfloat16 tile[64][264]; // px x 256-ic half, pad 264 (33.8 KB)
    const int y = r - 1;
    const float* xb = x + (size_t)b * IC * HW * HW + (size_t)y * 64;
    const int w = t >> 6, l = t & 63;

    for (int h = 0; h < 2; ++h) {
        // fill: 256 ic x 64 px
        for (int k = 0; k < 16; ++k) {
            int ic = k * 16 + (t >> 4);
            int px = (t & 15) * 4;
            float4 v = *(const float4*)(xb + (size_t)(h * 256 + ic) * 4096 + px);
            tile[px][ic]     = __float2bfloat16(v.x);
            tile[px + 1][ic] = __float2bfloat16(v.y);
            tile[px + 2][ic] = __float2bfloat16(v.z);
            tile[px + 3][ic] = __float2bfloat16(v.w);
        }
        __syncthreads();
        // write: col c -> dst[c*512 + h*256 + ...]; lane l writes 8B (4 ic)
        short4v z = {0, 0, 0, 0};
        for (int c = w; c < 66; c += 4) {
            short4v val;
            if (c == 0 || c == 65) val = z;
            else val = *(const short4v*)&tile[c - 1][l * 4];
            *(short4v*)(dst + (size_t)c * 512 + h * 256 + l * 4) = val;
        }
        __syncthreads();
    }
}

// ---------------- wmod2: [b][tap][ocf32][icc16][ol16][l4p4][j8] bf16 ----------------
// A-load: wave reads 1KB contiguous. grid (OC), 256 threads, loops b,tap.
__global__ __launch_bounds__(256) void k_wmod2(
    const float* __restrict__ weight, const float* __restrict__ s,
    const float* __restrict__ dmod, __hip_bfloat16* __restrict__ wm) {
    __shared__ float wrow[IC * 9]; // 18KB
    const int oc = blockIdx.x;
    const float* wp = weight + (size_t)oc * IC * 9;
    for (int i = threadIdx.x; i < IC * 9; i += 256) wrow[i] = wp[i];
    __syncthreads();
    const int ocf = oc >> 4, ol = oc & 15;
    const int icp = threadIdx.x, ic0 = icp * 2;
    const int icc = ic0 >> 5, l4p = (ic0 >> 3) & 3, j = ic0 & 7;

    for (int b = 0; b < BATCH; ++b) {
        float dd = CONV_SCALE * dmod[b * OC + oc];
        float2 sv = *(const float2*)(s + (size_t)b * IC + ic0);
        float m0 = sv.x * dd, m1 = sv.y * dd;
#pragma unroll
        for (int tap = 0; tap < 9; ++tap) {
            float v0 = wrow[ic0 * 9 + tap] * m0;
            float v1 = wrow[(ic0 + 1) * 9 + tap] * m1;
            __hip_bfloat162 p;
            p.x = __float2bfloat16(v0);
            p.y = __float2bfloat16(v1);
            size_t off = (((((size_t)(b * 9 + tap) * 32 + ocf) * 16 + icc) * 16 + ol) * 4 + l4p) * 8 + j;
            *(__hip_bfloat162*)(wm + off) = p;
        }
    }
}

// ---------------- conv v2: async-staged, double-buffered MFMA implicit GEMM ----------------
// 512 blocks = (b:16 x ocg:4) x sp:8; 512 threads (8 waves); tile 128oc x 8row x 64col.
// LDS x tile [ichi4][row10][col66][j8] bf16, double buffered (84.5 KB).
__global__ __launch_bounds__(512, 2) void k_conv_mfma2(
    const __hip_bfloat16* __restrict__ xt, const __hip_bfloat16* __restrict__ wm,
    float* __restrict__ out) {
    __shared__ short xs[2][2640 * 8]; // 2 x 42.24 KB

    const int bid = blockIdx.x;
    const int g = bid & 63, sp = bid >> 6; // bid%8 const per (b,ocg) -> same XCD
    const int b = g >> 2, ocg = g & 3;
    const int ocb128 = ocg * 8; // ocf base (128 oc = 8 ocf)
    const int y0 = sp * 8;

    const int t = threadIdx.x;
    const int lane = t & 63, wid = t >> 6;
    const int og = wid >> 2, rg = wid & 3;
    const int l15 = lane & 15, l4 = lane >> 4;

    const __hip_bfloat16* xtb = xt + (size_t)b * 66 * 66 * 512;
    const __hip_bfloat16* wb = wm + (size_t)b * 9 * OC * IC;

    f32x4 acc[4][8];
#pragma unroll
    for (int m = 0; m < 4; ++m)
#pragma unroll
        for (int n = 0; n < 8; ++n) acc[m][n] = (f32x4){0.f, 0.f, 0.f, 0.f};

    // async stage one 32-ic chunk into xs[buf]
    auto stage = [&](int buf, int icb) {
        for (int i = t; i < 2640; i += 512) {
            int ichi = i / 660;
            int rem = i - ichi * 660;
            int row = rem / 66;
            int col = rem - row * 66;
            const __hip_bfloat16* src =
                xtb + ((size_t)((y0 + row) * 66 + col) * 512 + icb + ichi * 8);
            __builtin_amdgcn_global_load_lds(
                (const __attribute__((address_space(1))) unsigned int*)src,
                (__attribute__((address_space(3))) unsigned int*)&xs[buf][i * 8], 16, 0, 0);
        }
    };

    stage(0, 0);
    asm volatile("s_waitcnt vmcnt(0)" ::: "memory");
    __syncthreads();

    for (int c = 0; c < 16; ++c) {
        const int buf = c & 1;
        if (c < 15) stage(buf ^ 1, (c + 1) * 32);

#pragma unroll
        for (int kw = 0; kw < 3; ++kw) {
            short8 A[3][4];
#pragma unroll
            for (int kh = 0; kh < 3; ++kh)
#pragma unroll
                for (int mt = 0; mt < 4; ++mt) {
                    int tap = kh * 3 + kw;
                    int ocf = ocb128 + og * 4 + mt;
                    A[kh][mt] = *(const short8*)(wb +
                        (((size_t)(tap * 32 + ocf) * 16 + c) * 512 + l15 * 32 + l4 * 8));
                }
#pragma unroll
            for (int cg = 0; cg < 4; ++cg) {
                short8 Bf[4];
#pragma unroll
                for (int ir = 0; ir < 4; ++ir) {
                    int row = rg * 2 + ir;
                    int col = cg * 16 + l15 + kw;
                    Bf[ir] = *(const short8*)&xs[buf][(l4 * 660 + row * 66 + col) * 8];
                }
#pragma unroll
                for (int kh = 0; kh < 3; ++kh)
#pragma unroll
                    for (int mt = 0; mt < 4; ++mt)
#pragma unroll
                        for (int r = 0; r < 2; ++r)
                            acc[mt][r * 4 + cg] = __builtin_amdgcn_mfma_f32_16x16x32_bf16(
                                A[kh][mt], Bf[r + kh], acc[mt][r * 4 + cg], 0, 0, 0);
            }
        }
        asm volatile("s_waitcnt vmcnt(0)" ::: "memory");
        __syncthreads();
    }

    // epilogue: C/D col=lane&15 (px), row=(lane>>4)*4+q (oc)
#pragma unroll
    for (int mt = 0; mt < 4; ++mt)
#pragma unroll
        for (int r = 0; r < 2; ++r)
#pragma unroll
            for (int cg = 0; cg < 4; ++cg) {
                f32x4 v = acc[mt][r * 4 + cg];
                int y = y0 + rg * 2 + r;
                int xcol = cg * 16 + l15;
#pragma unroll
                for (int q = 0; q < 4; ++q) {
                    int oc = ocg * 128 + og * 64 + mt * 16 + l4 * 4 + q;
                    out[(((size_t)b * OC + oc) * HW + y) * HW + xcol] = v[q];
                }
            }
}

// ================= fallback path (round-3, known-good 686us) =================
__global__ __launch_bounds__(256) void k_wmod(
    const float* __restrict__ weight, const float* __restrict__ s,
    const float* __restrict__ dmod, __hip_bfloat16* __restrict__ wmod) {
    __shared__ float wrow[IC * 9];
    int oc = blockIdx.x, b = blockIdx.y;
    const float* wp = weight + (size_t)oc * IC * 9;
    for (int i = threadIdx.x; i < IC * 9; i += 256) wrow[i] = wp[i];
    __syncthreads();
    float dd = CONV_SCALE * dmod[b * OC + oc];
    const float* sb = s + (size_t)b * IC;
#pragma unroll
    for (int tap = 0; tap < 9; ++tap) {
        int ic0 = threadIdx.x * 2;
        float v0 = wrow[ic0 * 9 + tap] * (sb[ic0] * dd);
        float v1 = wrow[(ic0 + 1) * 9 + tap] * (sb[ic0 + 1] * dd);
        __hip_bfloat162 p;
        p.x = __float2bfloat16(v0);
        p.y = __float2bfloat16(v1);
        *(__hip_bfloat162*)(wmod + ((((size_t)b * 9 + tap) * OC + oc) * IC + ic0)) = p;
    }
}

__global__ __launch_bounds__(512, 2) void k_conv_mfma(
    const float* __restrict__ x, const __hip_bfloat16* __restrict__ wmod,
    float* __restrict__ out) {
    __shared__ short xs[4 * 10 * 66 * 8];
    const int bid = blockIdx.x;
    const int g = bid & 63, sp = bid >> 6;
    const int b = g >> 2, ocg = g & 3;
    const int ocb = ocg * 128, y0 = sp * 8;
    const int t = threadIdx.x;
    const int lane = t & 63, wid = t >> 6;
    const int og = wid >> 2, rg = wid & 3;
    const int l15 = lane & 15, l4 = lane >> 4;
    f32x4 acc[4][8];
#pragma unroll
    for (int m = 0; m < 4; ++m)
#pragma unroll
        for (int n = 0; n < 8; ++n) acc[m][n] = (f32x4){0.f, 0.f, 0.f, 0.f};
    const float* xb = x + (size_t)b * IC * HW * HW;
    const __hip_bfloat16* wb = wmod + (size_t)b * 9 * OC * IC;
    for (int icb = 0; icb < IC; icb += 32) {
        __syncthreads();
        for (int i = t; i < 2640; i += 512) {
            int ichi = i / 660;
            int rem = i - ichi * 660;
            int row = rem / 66;
            int col = rem - row * 66;
            int gy = y0 + row - 1, gx = col - 1;
            float v[8];
            if ((unsigned)gy < 64u && (unsigned)gx < 64u) {
                const float* xp = xb + ((size_t)(icb + ichi * 8) * 64 + gy) * 64 + gx;
#pragma unroll
                for (int j = 0; j < 8; ++j) v[j] = xp[(size_t)j * 4096];
            } else {
#pragma unroll
                for (int j = 0; j < 8; ++j) v[j] = 0.f;
            }
            short8 pk;
#pragma unroll
            for (int j = 0; j < 8; ++j) {
                __hip_bfloat16 bh = __float2bfloat16(v[j]);
                pk[j] = *reinterpret_cast<short*>(&bh);
            }
            *(short8*)&xs[i * 8] = pk;
        }
        __syncthreads();
#pragma unroll
        for (int kw = 0; kw < 3; ++kw) {
            short8 A[3][4];
#pragma unroll
            for (int kh = 0; kh < 3; ++kh)
#pragma unroll
                for (int mt = 0; mt < 4; ++mt) {
                    int oc = ocb + og * 64 + mt * 16 + l15;
                    int tap = kh * 3 + kw;
                    A[kh][mt] = *(const short8*)(wb + (((size_t)tap * OC + oc) * IC + icb + l4 * 8));
                }
#pragma unroll
            for (int cg = 0; cg < 4; ++cg) {
                short8 Bf[4];
#pragma unroll
                for (int ir = 0; ir < 4; ++ir) {
                    int row = rg * 2 + ir;
                    int col = cg * 16 + l15 + kw;
                    Bf[ir] = *(const short8*)&xs[(((l4 * 10 + row) * 66 + col)) * 8];
                }
#pragma unroll
                for (int kh = 0; kh < 3; ++kh)
#pragma unroll
                    for (int mt = 0; mt < 4; ++mt)
#pragma unroll
                        for (int r = 0; r < 2; ++r)
                            acc[mt][r * 4 + cg] = __builtin_amdgcn_mfma_f32_16x16x32_bf16(
                                A[kh][mt], Bf[r + kh], acc[mt][r * 4 + cg], 0, 0, 0);
            }
        }
    }
#pragma unroll
    for (int mt = 0; mt < 4; ++mt)
#pragma unroll
        for (int r = 0; r < 2; ++r)
#pragma unroll
            for (int cg = 0; cg < 4; ++cg) {
                f32x4 v = acc[mt][r * 4 + cg];
                int y = y0 + rg * 2 + r;
                int xcol = cg * 16 + l15;
#pragma unroll
                for (int q = 0; q < 4; ++q) {
                    int oc = ocb + og * 64 + mt * 16 + l4 * 4 + q;
                    out[(((size_t)b * OC + oc) * HW + y) * HW + xcol] = v[q];
                }
            }
}

#define OC_TILE 16
#define ROWS 4
#define ICCH 8
#define XW 67
__global__ __launch_bounds__(256) void k_conv_f32(
    const float* __restrict__ x, const float* __restrict__ weight,
    const float* __restrict__ s, const float* __restrict__ dmod,
    float* __restrict__ out) {
    __shared__ float x_lds[ICCH][ROWS + 2][XW];
    __shared__ float w_lds[OC_TILE][ICCH][9];
    const int b = blockIdx.z;
    const int ocb = blockIdx.y * OC_TILE;
    const int y0 = blockIdx.x * ROWS;
    const int t = threadIdx.x;
    const int gg = t & 63;
    const int ocg = t >> 6;
    const int row = gg >> 4;
    const int col = (gg & 15) * 4;
    float acc[4][4];
#pragma unroll
    for (int j = 0; j < 4; ++j)
#pragma unroll
        for (int i = 0; i < 4; ++i) acc[j][i] = 0.f;
    const float* xb = x + (size_t)b * IC * HW * HW;
    const float* sb = s + (size_t)b * IC;
    const float* db = dmod + (size_t)b * OC;
    for (int icb = 0; icb < IC; icb += ICCH) {
        for (int i = t; i < ICCH * 6 * 66; i += 256) {
            int ic = i / (6 * 66);
            int rem = i - ic * (6 * 66);
            int r = rem / 66;
            int cx = rem - r * 66;
            int gy = y0 + r - 1;
            int gx = cx - 1;
            float v = 0.f;
            if ((unsigned)gy < 64u && (unsigned)gx < 64u)
                v = xb[((size_t)(icb + ic) * 64 + gy) * 64 + gx];
            x_lds[ic][r][cx] = v;
        }
        for (int i = t; i < OC_TILE * ICCH * 9; i += 256) {
            int oc = i / (ICCH * 9);
            int rem = i - oc * (ICCH * 9);
            int ic = rem / 9;
            int kk = rem - ic * 9;
            float sc = CONV_SCALE * sb[icb + ic] * db[ocb + oc];
            w_lds[oc][ic][kk] = weight[((size_t)(ocb + oc) * IC + (icb + ic)) * 9 + kk] * sc;
        }
        __syncthreads();
#pragma unroll
        for (int ic = 0; ic < ICCH; ++ic)
#pragma unroll
            for (int kh = 0; kh < 3; ++kh) {
                float xv[6];
#pragma unroll
                for (int u = 0; u < 6; ++u) xv[u] = x_lds[ic][row + kh][col + u];
#pragma unroll
                for (int kw = 0; kw < 3; ++kw)
#pragma unroll
                    for (int j = 0; j < 4; ++j) {
                        float wv = w_lds[ocg * 4 + j][ic][kh * 3 + kw];
#pragma unroll
                        for (int i2 = 0; i2 < 4; ++i2)
                            acc[j][i2] = fmaf(wv, xv[i2 + kw], acc[j][i2]);
                    }
            }
        __syncthreads();
    }
#pragma unroll
    for (int j = 0; j < 4; ++j) {
        int oc = ocb + ocg * 4 + j;
        float4 v = make_float4(acc[j][0], acc[j][1], acc[j][2], acc[j][3]);
        *(float4*)(out + (((size_t)b * OC + oc) * HW + (y0 + row)) * HW + col) = v;
    }
}

extern "C" void kernel_launch(void* const* d_in, const int* in_sizes, int n_in,
                              void* d_out, int out_size, void* d_ws, size_t ws_size,
                              hipStream_t stream) {
    const float* x      = (const float*)d_in[0];
    const float* style  = (const float*)d_in[1];
    const float* weight = (const float*)d_in[2];
    const float* mod_w  = (const float*)d_in[3];
    const float* mod_b  = (const float*)d_in[4];
    float* out = (float*)d_out;

    float* s    = (float*)d_ws;
    float* wsq  = s + BATCH * IC;
    float* dmod = wsq + (size_t)OC * IC;
    __hip_bfloat16* wmod = (__hip_bfloat16*)(dmod + BATCH * OC);
    const size_t base_bytes = (size_t)(BATCH * IC + OC * IC + BATCH * OC) * 4;
    const size_t wmod_bytes = (size_t)BATCH * 9 * OC * IC * 2;
    const size_t xt_bytes   = (size_t)BATCH * 66 * 66 * 512 * 2;
    __hip_bfloat16* xt = (__hip_bfloat16*)((char*)d_ws + base_bytes + wmod_bytes);

    k_style<<<(BATCH * IC + 255) / 256, 256, 0, stream>>>(style, mod_w, mod_b, s);
    k_wsq<<<(OC * IC + 255) / 256, 256, 0, stream>>>(weight, wsq);
    k_demod<<<(BATCH * OC + 255) / 256, 256, 0, stream>>>(s, wsq, dmod);

    if (ws_size >= base_bytes + wmod_bytes + xt_bytes) {
        k_wmod2<<<OC, 256, 0, stream>>>(weight, s, dmod, wmod);
        dim3 xg(66, BATCH);
        k_xt<<<xg, 256, 0, stream>>>(x, xt);
        k_conv_mfma2<<<512, 512, 0, stream>>>(xt, wmod, out);
    } else if (ws_size >= base_bytes + wmod_bytes) {
        dim3 wg(OC, BATCH);
        k_wmod<<<wg, 256, 0, stream>>>(weight, s, dmod, wmod);
        k_conv_mfma<<<512, 512, 0, stream>>>(x, wmod, out);
    } else {
        dim3 grid(HW / ROWS, OC / OC_TILE, BATCH);
        k_conv_f32<<<grid, 256, 0, stream>>>(x, weight, s, dmod, out);
    }
}